// Round 9
// baseline (263.222 us; speedup 1.0000x reference)
//
#include <hip/hip_runtime.h>

#define NN 8192
#define DD 128
#define MAXCLS 64   // max members per class; Binom(8192,1/1024) mean 8 -> P(>64) negligible
#define NCHUNK 8    // j-chunks; grid = NCHUNK x 64 = 512 blocks = exactly 2/CU
#define GRID 512
#define LOG2E 1.4426950408889634f
#define E1    2.718281828459045f   // e^margin, margin = 1

typedef __attribute__((ext_vector_type(8))) short bf16x8;
typedef __attribute__((ext_vector_type(4))) float f32x4;

#if __has_builtin(__builtin_amdgcn_exp2f)
#define EXP2F(x) __builtin_amdgcn_exp2f(x)
#else
#define EXP2F(x) exp2f(x)
#endif

// Agent(device)-scope memory fences (__hip_atomic_fence not declared on this ROCm).
#if __has_builtin(__builtin_amdgcn_fence)
#define FENCE_REL() __builtin_amdgcn_fence(__ATOMIC_RELEASE, "agent")
#define FENCE_ACQ() __builtin_amdgcn_fence(__ATOMIC_ACQUIRE, "agent")
#else
#define FENCE_REL() __threadfence()
#define FENCE_ACQ() __threadfence()
#endif

// async global->LDS 16B: lane L's 16B lands at (wave-uniform) lptr + L*16
__device__ __forceinline__ void load16_lds(const unsigned short* g, unsigned short* l) {
    __builtin_amdgcn_global_load_lds(
        (const __attribute__((address_space(1))) unsigned int*)g,
        (__attribute__((address_space(3))) unsigned int*)l,
        16, 0, 0);
}

__device__ __forceinline__ unsigned short f2bf(float x) {
    unsigned u = __float_as_uint(x);
    u = (u + 0x7FFFu + ((u >> 16) & 1u)) >> 16;
    return (unsigned short)u;
}

// Device-wide barrier. Co-residency by construction: grid=512=2x256CU,
// launch_bounds(256,2), LDS 66KB<=80KB -> exactly 2 blocks/CU, all resident.
// R9 fix: poll with device-scope atomic LOAD (broadcasts in L2, no serialization).
// R8 polled with atomicAdd(slot,0) -- a returning RMW; 512 spinners saturated the
// L2 atomic unit and the barrier cost ~70us each. Loads don't occupy the RMW queue,
// so the 512 arrival increments (spread by phase skew anyway) complete immediately.
__device__ __forceinline__ void grid_barrier(unsigned int* slot) {
    FENCE_REL();
    __syncthreads();
    if (threadIdx.x == 0) {
        __hip_atomic_fetch_add(slot, 1u, __ATOMIC_ACQ_REL, __HIP_MEMORY_SCOPE_AGENT);
        while (__hip_atomic_load(slot, __ATOMIC_ACQUIRE, __HIP_MEMORY_SCOPE_AGENT) < (unsigned)GRID)
            __builtin_amdgcn_s_sleep(4);
    }
    __syncthreads();
    FENCE_ACQ();
}

// ==================== mega-kernel: convert+bucket | GEMM+V | pairs+finalize ====================
__global__ __launch_bounds__(256, 2) void ml_mega_kernel(
    const float* __restrict__ a, const float* __restrict__ b,
    const int* __restrict__ labels,
    unsigned short* __restrict__ abf, unsigned short* __restrict__ bbf,
    int* __restrict__ cnt, int* __restrict__ list, float* __restrict__ Vp,
    float* __restrict__ classLoss, int* __restrict__ classCnt,
    unsigned int* __restrict__ bar, unsigned int* __restrict__ done,
    float* __restrict__ out)
{
    __shared__ union {
        struct {                                   // GEMM phase: 66 KB
            unsigned short As[128 * DD];           // 32 KB
            unsigned short Bs[2][64 * DD];         // 2 x 16 KB
            float red[2][64];
        } g;
        struct {                                   // pairs phase: ~17 KB (aliases)
            float Sc[MAXCLS * MAXCLS];             // 16 KB
            int   mem[MAXCLS];
            float sumExp[MAXCLS];
            float vadj[MAXCLS];
            float ps[4];  int cs[4];
            double dred[4];  long long cred[4];
        } p;
    } sh;

    const int tid  = threadIdx.x;
    const int lane = tid & 63;
    const int wv   = tid >> 6;

    // ---------------- phase 1: fp32 -> bf16 convert (A pre-scaled by log2e) + bucket ----------------
    {
        const int gid = blockIdx.x * 256 + tid;    // 0 .. 131071
#pragma unroll
        for (int it = 0; it < 4; it++) {
            int t = it * 131072 + gid;             // 0 .. 524287 (float4 units over 2x 1M floats)
            const float* src = a;
            unsigned short* dst = abf;
            int idx = t;
            float scale = LOG2E;
            if (t >= 262144) { src = b; dst = bbf; idx = t - 262144; scale = 1.0f; }
            float4 v = ((const float4*)src)[idx];
            ushort4 o;
            o.x = f2bf(v.x * scale); o.y = f2bf(v.y * scale);
            o.z = f2bf(v.z * scale); o.w = f2bf(v.w * scale);
            ((ushort4*)dst)[idx] = o;
        }
        if (gid < NN) {                            // bucket append (cnt zeroed by memset node)
            int c = labels[gid];
            int p0 = atomicAdd(&cnt[c], 1);
            if (p0 < MAXCLS) list[c * MAXCLS + p0] = gid;
        }
    }

    grid_barrier(&bar[0]);

    // ---------------- phase 2: flash-style GEMM + unmasked exp2 row-sum -> Vp ----------------
    // R6 structure: double-buffered 64-col B tiles, XOR-swizzled LDS,
    // global_load_lds w=16, A fragments register-resident.
    {
        const int row0 = (blockIdx.x & 63) * 128;
        const int j0   = (blockIdx.x >> 6) * 1024;

        const int lr = lane >> 4;      // staging: row-within-4
        const int sp = lane & 15;      // staging: slot
        const int m  = lane & 15;      // mfma row/col lane
        const int q  = lane >> 4;
        const int xr = m & 7;          // read-side swizzle key

#pragma unroll
        for (int i = 0; i < 8; i++) {
            int rb = wv * 32 + i * 4;
            int r  = rb + lr;
            int cc = sp ^ (r & 7);
            load16_lds(&abf[(size_t)(row0 + r) * DD + cc * 8], &sh.g.As[rb * DD]);
        }
#pragma unroll
        for (int i = 0; i < 4; i++) {
            int rb = wv * 16 + i * 4;
            int r  = rb + lr;
            int cc = sp ^ (r & 7);
            load16_lds(&bbf[(size_t)(j0 + r) * DD + cc * 8], &sh.g.Bs[0][rb * DD]);
        }
#pragma unroll
        for (int i = 0; i < 4; i++) {
            int rb = wv * 16 + i * 4;
            int r  = rb + lr;
            int cc = sp ^ (r & 7);
            load16_lds(&bbf[(size_t)(j0 + 64 + r) * DD + cc * 8], &sh.g.Bs[1][rb * DD]);
        }
        __syncthreads();

        const int wi = (wv >> 1) * 64;   // row-half
        const int wj = (wv & 1) * 32;    // col-half of the 64-col tile

        bf16x8 afr[4][4];
#pragma unroll
        for (int ti = 0; ti < 4; ti++)
#pragma unroll
            for (int ks = 0; ks < 4; ks++) {
                int r   = wi + ti * 16 + m;
                int pos = (ks * 4 + q) ^ xr;
                afr[ti][ks] = *(const bf16x8*)(&sh.g.As[r * DD + pos * 8]);
            }

        float rs[4][4];
#pragma unroll
        for (int ti = 0; ti < 4; ti++)
#pragma unroll
            for (int rg = 0; rg < 4; rg++) rs[ti][rg] = 0.f;

        const f32x4 zero = {0.f, 0.f, 0.f, 0.f};

#pragma unroll 2
        for (int jt = 0; jt < 16; jt++) {
            const int pb = jt & 1;
            f32x4 acc[4][2];
#pragma unroll
            for (int ti = 0; ti < 4; ti++)
#pragma unroll
                for (int tj = 0; tj < 2; tj++) acc[ti][tj] = zero;

#pragma unroll
            for (int ks = 0; ks < 4; ks++) {
                bf16x8 bfr[2];
#pragma unroll
                for (int tj = 0; tj < 2; tj++) {
                    int r   = wj + tj * 16 + m;
                    int pos = (ks * 4 + q) ^ xr;
                    bfr[tj] = *(const bf16x8*)(&sh.g.Bs[pb][r * DD + pos * 8]);
                }
#pragma unroll
                for (int ti = 0; ti < 4; ti++)
#pragma unroll
                    for (int tj = 0; tj < 2; tj++)
                        acc[ti][tj] = __builtin_amdgcn_mfma_f32_16x16x32_bf16(afr[ti][ks], bfr[tj], acc[ti][tj], 0, 0, 0);
            }

#pragma unroll
            for (int ti = 0; ti < 4; ti++)
#pragma unroll
                for (int tj = 0; tj < 2; tj++) {
                    f32x4 c = acc[ti][tj];
                    rs[ti][0] += EXP2F(c[0]);
                    rs[ti][1] += EXP2F(c[1]);
                    rs[ti][2] += EXP2F(c[2]);
                    rs[ti][3] += EXP2F(c[3]);
                }

            __syncthreads();   // drains prefetch issued ~1 tile ago + all reads of buf[pb] done
            if (jt < 14) {
                int jb = j0 + (jt + 2) * 64;
#pragma unroll
                for (int i = 0; i < 4; i++) {
                    int rb = wv * 16 + i * 4;
                    int r  = rb + lr;
                    int cc = sp ^ (r & 7);
                    load16_lds(&bbf[(size_t)(jb + r) * DD + cc * 8], &sh.g.Bs[pb][rb * DD]);
                }
            }
        }

#pragma unroll
        for (int ti = 0; ti < 4; ti++)
#pragma unroll
            for (int rg = 0; rg < 4; rg++) {
                float v = rs[ti][rg];
                v += __shfl_xor(v, 1);
                v += __shfl_xor(v, 2);
                v += __shfl_xor(v, 4);
                v += __shfl_xor(v, 8);
                rs[ti][rg] = v;
            }

        if ((wv & 1) == 1 && m == 0) {
#pragma unroll
            for (int ti = 0; ti < 4; ti++)
#pragma unroll
                for (int rg = 0; rg < 4; rg++)
                    sh.g.red[wv >> 1][ti * 16 + q * 4 + rg] = rs[ti][rg];
        }
        __syncthreads();
        if ((wv & 1) == 0 && m == 0) {
#pragma unroll
            for (int ti = 0; ti < 4; ti++)
#pragma unroll
                for (int rg = 0; rg < 4; rg++) {
                    int rloc = ti * 16 + q * 4 + rg;
                    Vp[(size_t)(blockIdx.x >> 6) * NN + row0 + wi + rloc] = rs[ti][rg] + sh.g.red[wv >> 1][rloc];
                }
        }
    }

    grid_barrier(&bar[1]);

    // ---------------- phase 3: per-class exact fp32 dots, V-adjust, hinge^2 ----------------
    // 2 classes per block; per-class slot writes (no same-address atomics); last-done reduce.
    float blkLoss[2];
    int   blkCnt[2];

#pragma unroll 1
    for (int rep = 0; rep < 2; rep++) {
        const int c = blockIdx.x * 2 + rep;
        __syncthreads();                       // Sc reuse across reps / after GEMM LDS use

        int mc = cnt[c];
        if (mc > MAXCLS) mc = MAXCLS;

        float vsum = 0.f;
        if (tid < mc) {
            int r = list[c * MAXCLS + tid];
            sh.p.mem[tid] = r;
#pragma unroll
            for (int jc = 0; jc < NCHUNK; jc++) vsum += Vp[(size_t)jc * NN + r];
        }
        if (tid < MAXCLS) sh.p.sumExp[tid] = 0.f;
        __syncthreads();

        // mc^2 dots (16-lane groups), cache S, accumulate exp sums
        const int g = tid >> 4;
        const int l = tid & 15;
        const int tot1 = mc * mc;
        for (int pp = g; pp < tot1; pp += 16) {
            int i = pp / mc;
            int j = pp - i * mc;
            int ri = sh.p.mem[i], rj = sh.p.mem[j];
            const float4* ar = (const float4*)(a + (size_t)ri * DD) + l * 2;
            const float4* br = (const float4*)(b + (size_t)rj * DD) + l * 2;
            float4 a0 = ar[0], a1 = ar[1];
            float4 b0 = br[0], b1 = br[1];
            float s = 0.f;
            s = fmaf(a0.x, b0.x, s); s = fmaf(a0.y, b0.y, s);
            s = fmaf(a0.z, b0.z, s); s = fmaf(a0.w, b0.w, s);
            s = fmaf(a1.x, b1.x, s); s = fmaf(a1.y, b1.y, s);
            s = fmaf(a1.z, b1.z, s); s = fmaf(a1.w, b1.w, s);
            s += __shfl_xor(s, 1);
            s += __shfl_xor(s, 2);
            s += __shfl_xor(s, 4);
            s += __shfl_xor(s, 8);
            if (l == 0) {
                sh.p.Sc[i * MAXCLS + j] = s;
                atomicAdd(&sh.p.sumExp[i], __expf(s));
            }
        }
        __syncthreads();

        if (tid < mc) sh.p.vadj[tid] = E1 * (vsum - sh.p.sumExp[tid]);
        __syncthreads();

        float partial = 0.f;
        int   count   = 0;
        for (int pp = tid; pp < tot1; pp += 256) {
            int i = pp / mc;
            int j = pp - i * mc;
            if (i != j) {
                float h = fmaxf(logf(sh.p.vadj[i] + sh.p.vadj[j]) - sh.p.Sc[i * MAXCLS + j], 0.f);
                partial += h * h;
                count++;
            }
        }
        for (int off = 32; off > 0; off >>= 1) {
            partial += __shfl_down(partial, off);
            count   += __shfl_down(count, off);
        }
        if (lane == 0) { sh.p.ps[wv] = partial; sh.p.cs[wv] = count; }
        __syncthreads();
        blkLoss[rep] = sh.p.ps[0] + sh.p.ps[1] + sh.p.ps[2] + sh.p.ps[3];
        blkCnt[rep]  = sh.p.cs[0] + sh.p.cs[1] + sh.p.cs[2] + sh.p.cs[3];
    }

    if (tid == 0) {
        atomicExch(&classLoss[blockIdx.x * 2 + 0], blkLoss[0]);   // device-scope visible slots
        atomicExch(&classCnt [blockIdx.x * 2 + 0], blkCnt[0]);
        atomicExch(&classLoss[blockIdx.x * 2 + 1], blkLoss[1]);
        atomicExch(&classCnt [blockIdx.x * 2 + 1], blkCnt[1]);
    }
    __syncthreads();

    // ---- last block reduces the 1024 class slots ----
    if (tid == 0) sh.p.ps[0] = (float)atomicAdd(done, 1u);
    __syncthreads();
    if ((unsigned)sh.p.ps[0] == (unsigned)(GRID - 1)) {
        double dls = 0.0;
        long long dct = 0;
        for (int k = tid; k < 1024; k += 256) {
            dls += (double)atomicAdd(&classLoss[k], 0.0f);   // coherent reads (distinct addrs)
            dct += (long long)atomicAdd(&classCnt[k], 0);
        }
        for (int off = 32; off > 0; off >>= 1) {
            dls += __shfl_down(dls, off);
            dct += __shfl_down(dct, off);
        }
        if (lane == 0) { sh.p.dred[wv] = dls; sh.p.cred[wv] = dct; }
        __syncthreads();
        if (tid == 0) {
            double ls = sh.p.dred[0] + sh.p.dred[1] + sh.p.dred[2] + sh.p.dred[3];
            long long np = sh.p.cred[0] + sh.p.cred[1] + sh.p.cred[2] + sh.p.cred[3];
            out[0] = (float)(ls / (2.0 * (double)np));
        }
    }
}

// ---------------- launch ----------------
extern "C" void kernel_launch(void* const* d_in, const int* in_sizes, int n_in,
                              void* d_out, int out_size, void* d_ws, size_t ws_size,
                              hipStream_t stream)
{
    const float* a      = (const float*)d_in[0];
    const float* b      = (const float*)d_in[1];
    const int*   labels = (const int*)d_in[2];
    float* out = (float*)d_out;

    char* ws = (char*)d_ws;
    // ws layout:
    //   [0, 2MB)   a_bf16 (scaled by log2e)    [2MB, 4MB)  b_bf16
    //   base2 = 4MB:
    //     +0       cnt[1024]            4096 B   (memset 0)
    //     +4096    bar[2] uint             8 B   (memset 0)
    //     +4112    done (uint)             4 B   (memset 0)
    //     +8192    classLoss[1024] f32  4096 B   (written unconditionally)
    //     +12288   classCnt[1024] int   4096 B
    //     +16384   list[1024*64]        256 KB
    //     +278528  Vp[8*8192] f32       256 KB
    unsigned short* abf = (unsigned short*)ws;
    unsigned short* bbf = (unsigned short*)(ws + 2097152);
    char*     base2     = ws + 4194304;
    int*      cnt       = (int*)(base2);
    unsigned* bar       = (unsigned*)(base2 + 4096);
    unsigned* done      = (unsigned*)(base2 + 4112);
    float*    classLoss = (float*)(base2 + 8192);
    int*      classCnt  = (int*)(base2 + 12288);
    int*      list      = (int*)(base2 + 16384);
    float*    Vp        = (float*)(base2 + 278528);

    (void)hipMemsetAsync(base2, 0, 4128, stream);

    ml_mega_kernel<<<GRID, 256, 0, stream>>>(a, b, labels, abf, bbf,
                                             cnt, list, Vp, classLoss, classCnt,
                                             bar, done, out);
}

// Round 10
// 118.177 us; speedup vs baseline: 2.2274x; 2.2274x over previous
//
#include <hip/hip_runtime.h>

#define NN 8192
#define DD 128
#define MAXCLS 64   // max members per class; Binom(8192,1/1024) mean 8 -> P(>64) negligible
#define NCHUNK 8    // j-chunks; GEMM grid = NCHUNK x 128 = 1024 blocks, 3/CU resident
#define LOG2E 1.4426950408889634f
#define E1    2.718281828459045f   // e^margin, margin = 1

typedef __attribute__((ext_vector_type(8))) short bf16x8;
typedef __attribute__((ext_vector_type(4))) float f32x4;

#if __has_builtin(__builtin_amdgcn_exp2f)
#define EXP2F(x) __builtin_amdgcn_exp2f(x)
#else
#define EXP2F(x) exp2f(x)
#endif

// async global->LDS 16B: per-lane global address, LDS dest = wave-uniform base + lane*16
__device__ __forceinline__ void load16_lds(const unsigned short* g, unsigned short* l) {
    __builtin_amdgcn_global_load_lds(
        (const __attribute__((address_space(1))) unsigned int*)g,
        (__attribute__((address_space(3))) unsigned int*)l,
        16, 0, 0);
}

// ---------------- K0: fp32 -> bf16 (RNE) convert + class bucketing ----------------
__device__ __forceinline__ unsigned short f2bf(float x) {
    unsigned u = __float_as_uint(x);
    u = (u + 0x7FFFu + ((u >> 16) & 1u)) >> 16;
    return (unsigned short)u;
}

__global__ __launch_bounds__(256) void ml_convert_kernel(
    const float* __restrict__ a, const float* __restrict__ b,
    const int* __restrict__ labels,
    unsigned short* __restrict__ abf, unsigned short* __restrict__ bbf,
    int* __restrict__ cnt, int* __restrict__ list)
{
    int t = blockIdx.x * 256 + threadIdx.x;       // 0 .. 524287
    const float* src = a;
    unsigned short* dst = abf;
    int idx = t;
    float scale = LOG2E;                           // A rows carry the log2e factor
    if (t >= 262144) { src = b; dst = bbf; idx = t - 262144; scale = 1.0f; }
    float4 v = ((const float4*)src)[idx];
    ushort4 o;
    o.x = f2bf(v.x * scale); o.y = f2bf(v.y * scale);
    o.z = f2bf(v.z * scale); o.w = f2bf(v.w * scale);
    ((ushort4*)dst)[idx] = o;

    if (t < NN) {   // fused bucket append (cnt pre-zeroed by memset)
        int c = labels[t];
        int p = atomicAdd(&cnt[c], 1);
        if (p < MAXCLS) list[c * MAXCLS + p] = t;
    }
}

// ---------------- K1: flash-style GEMM + unmasked exp2 row-sum -> Vp partials ----------------
// R10: 64-row blocks (As 16 KB + dbuf Bs 32 KB = 48.5 KB LDS -> 3 blocks/CU, 3 waves/SIMD
// vs R6's 2) to hide the per-tile barrier drains. grid (NCHUNK, 128) = 1024 blocks.
// Wave layout 2x2: wi=(wv>>1)*32 row-half, wj=(wv&1)*32 col-half of each 64-col tile.
// LDS swizzle: row r, 16B-chunk c at pos (c ^ (r&7)) -> DMA-linear AND conflict-free b128
// (all row offsets multiples of 8, so read-side key xr = m&7 unchanged).
__global__ __launch_bounds__(256, 3) void ml_vsum_gemm_kernel(
    const unsigned short* __restrict__ abf, const unsigned short* __restrict__ bbf,
    float* __restrict__ Vp)
{
    __shared__ unsigned short As[64 * DD];        // 16 KB
    __shared__ unsigned short Bs[2][64 * DD];     // 2 x 16 KB
    __shared__ float red[2][32];                  // cross-wave V combine

    const int tid  = threadIdx.x;
    const int lane = tid & 63;
    const int wv   = tid >> 6;
    const int row0 = blockIdx.y * 64;
    const int j0   = blockIdx.x * 1024;

    const int lr = lane >> 4;      // staging: row-within-4
    const int sp = lane & 15;      // staging: slot
    const int m  = lane & 15;      // mfma row/col lane
    const int q  = lane >> 4;
    const int xr = m & 7;          // read-side swizzle key

    // ---- issue A (once) + B tiles 0,1 ----
#pragma unroll
    for (int i = 0; i < 4; i++) {
        int rb = wv * 16 + i * 4;
        int r  = rb + lr;
        int cc = sp ^ (r & 7);
        load16_lds(&abf[(size_t)(row0 + r) * DD + cc * 8], &As[rb * DD]);
    }
#pragma unroll
    for (int i = 0; i < 4; i++) {
        int rb = wv * 16 + i * 4;
        int r  = rb + lr;
        int cc = sp ^ (r & 7);
        load16_lds(&bbf[(size_t)(j0 + r) * DD + cc * 8], &Bs[0][rb * DD]);
    }
#pragma unroll
    for (int i = 0; i < 4; i++) {
        int rb = wv * 16 + i * 4;
        int r  = rb + lr;
        int cc = sp ^ (r & 7);
        load16_lds(&bbf[(size_t)(j0 + 64 + r) * DD + cc * 8], &Bs[1][rb * DD]);
    }
    __syncthreads();

    const int wi = (wv >> 1) * 32;   // row-half (0 or 32)
    const int wj = (wv & 1) * 32;    // col-half of the 64-col tile

    // ---- A fragments -> registers (read once): 2 row-tiles x 4 k-slices ----
    bf16x8 afr[2][4];
#pragma unroll
    for (int ti = 0; ti < 2; ti++)
#pragma unroll
        for (int ks = 0; ks < 4; ks++) {
            int r   = wi + ti * 16 + m;
            int pos = (ks * 4 + q) ^ xr;
            afr[ti][ks] = *(const bf16x8*)(&As[r * DD + pos * 8]);
        }

    float rs[2][4];
#pragma unroll
    for (int ti = 0; ti < 2; ti++)
#pragma unroll
        for (int rg = 0; rg < 4; rg++) rs[ti][rg] = 0.f;

    const f32x4 zero = {0.f, 0.f, 0.f, 0.f};

    // ---- j-tile loop: 16 tiles of 64 cols, double-buffered ----
#pragma unroll 2
    for (int jt = 0; jt < 16; jt++) {
        const int pb = jt & 1;
        f32x4 acc[2][2];
#pragma unroll
        for (int ti = 0; ti < 2; ti++)
#pragma unroll
            for (int tj = 0; tj < 2; tj++) acc[ti][tj] = zero;

#pragma unroll
        for (int ks = 0; ks < 4; ks++) {
            bf16x8 bfr[2];
#pragma unroll
            for (int tj = 0; tj < 2; tj++) {
                int r   = wj + tj * 16 + m;
                int pos = (ks * 4 + q) ^ xr;
                bfr[tj] = *(const bf16x8*)(&Bs[pb][r * DD + pos * 8]);
            }
#pragma unroll
            for (int ti = 0; ti < 2; ti++)
#pragma unroll
                for (int tj = 0; tj < 2; tj++)
                    acc[ti][tj] = __builtin_amdgcn_mfma_f32_16x16x32_bf16(afr[ti][ks], bfr[tj], acc[ti][tj], 0, 0, 0);
        }

        // epilogue: unmasked exp2 accumulate (A pre-scaled by log2e -> exp2(acc)=exp(S))
#pragma unroll
        for (int ti = 0; ti < 2; ti++)
#pragma unroll
            for (int tj = 0; tj < 2; tj++) {
                f32x4 c = acc[ti][tj];
                rs[ti][0] += EXP2F(c[0]);
                rs[ti][1] += EXP2F(c[1]);
                rs[ti][2] += EXP2F(c[2]);
                rs[ti][3] += EXP2F(c[3]);
            }

        __syncthreads();   // drains prefetch issued ~1 tile ago + all reads of buf[pb] done
        if (jt < 14) {
            int jb = j0 + (jt + 2) * 64;
#pragma unroll
            for (int i = 0; i < 4; i++) {
                int rb = wv * 16 + i * 4;
                int r  = rb + lr;
                int cc = sp ^ (r & 7);
                load16_lds(&bbf[(size_t)(jb + r) * DD + cc * 8], &Bs[pb][rb * DD]);
            }
        }
    }

    // ---- reduce over the 16 col-lanes ----
#pragma unroll
    for (int ti = 0; ti < 2; ti++)
#pragma unroll
        for (int rg = 0; rg < 4; rg++) {
            float v = rs[ti][rg];
            v += __shfl_xor(v, 1);
            v += __shfl_xor(v, 2);
            v += __shfl_xor(v, 4);
            v += __shfl_xor(v, 8);
            rs[ti][rg] = v;
        }

    // ---- cross-wave combine (col-half waves deposit; col-base waves add + store) ----
    if ((wv & 1) == 1 && m == 0) {
#pragma unroll
        for (int ti = 0; ti < 2; ti++)
#pragma unroll
            for (int rg = 0; rg < 4; rg++)
                red[wv >> 1][ti * 16 + q * 4 + rg] = rs[ti][rg];
    }
    __syncthreads();
    if ((wv & 1) == 0 && m == 0) {
#pragma unroll
        for (int ti = 0; ti < 2; ti++)
#pragma unroll
            for (int rg = 0; rg < 4; rg++) {
                int rloc = ti * 16 + q * 4 + rg;
                Vp[(size_t)blockIdx.x * NN + row0 + wi + rloc] = rs[ti][rg] + red[wv >> 1][rloc];
            }
    }
}

// ---------------- K2: per-class exact fp32 dots, V-adjust, hinge^2; slot writes ----------------
__global__ __launch_bounds__(256) void ml_pairs_kernel(
    const float* __restrict__ a, const float* __restrict__ b,
    const int* __restrict__ cnt, const int* __restrict__ list,
    const float* __restrict__ Vp,
    float* __restrict__ classLoss, int* __restrict__ classCnt,
    unsigned int* __restrict__ done, float* __restrict__ out)
{
    __shared__ int   mem[MAXCLS];
    __shared__ float sumExp[MAXCLS];
    __shared__ float Vadj[MAXCLS];
    __shared__ float Sc[MAXCLS * MAXCLS];   // 16 KB
    __shared__ float ps[4];
    __shared__ int   cs[4];
    __shared__ double dred[4];
    __shared__ long long cred[4];

    const int c   = blockIdx.x;
    const int tid = threadIdx.x;
    int mc = cnt[c];
    if (mc > MAXCLS) mc = MAXCLS;

    float vsum = 0.f;
    if (tid < mc) {
        int r = list[c * MAXCLS + tid];
        mem[tid] = r;
#pragma unroll
        for (int jc = 0; jc < NCHUNK; jc++) vsum += Vp[(size_t)jc * NN + r];
    }
    if (tid < MAXCLS) sumExp[tid] = 0.f;
    __syncthreads();

    // ---- phase 1: mc^2 dots (16-lane groups), cache S, accumulate exp sums ----
    const int g = tid >> 4;                   // 16 groups
    const int l = tid & 15;
    const int tot1 = mc * mc;
    for (int pp = g; pp < tot1; pp += 16) {
        int i = pp / mc;
        int j = pp - i * mc;
        int ri = mem[i], rj = mem[j];
        const float4* ar = (const float4*)(a + (size_t)ri * DD) + l * 2;
        const float4* br = (const float4*)(b + (size_t)rj * DD) + l * 2;
        float4 a0 = ar[0], a1 = ar[1];
        float4 b0 = br[0], b1 = br[1];
        float s = 0.f;
        s = fmaf(a0.x, b0.x, s); s = fmaf(a0.y, b0.y, s);
        s = fmaf(a0.z, b0.z, s); s = fmaf(a0.w, b0.w, s);
        s = fmaf(a1.x, b1.x, s); s = fmaf(a1.y, b1.y, s);
        s = fmaf(a1.z, b1.z, s); s = fmaf(a1.w, b1.w, s);
        s += __shfl_xor(s, 1);
        s += __shfl_xor(s, 2);
        s += __shfl_xor(s, 4);
        s += __shfl_xor(s, 8);
        if (l == 0) {
            Sc[i * MAXCLS + j] = s;
            atomicAdd(&sumExp[i], __expf(s));
        }
    }
    __syncthreads();

    if (tid < mc) Vadj[tid] = E1 * (vsum - sumExp[tid]);
    __syncthreads();

    // ---- phase 2: one thread per ordered pair (i != j) ----
    float partial = 0.f;
    int   count   = 0;
    for (int pp = tid; pp < tot1; pp += 256) {
        int i = pp / mc;
        int j = pp - i * mc;
        if (i != j) {
            float h = fmaxf(logf(Vadj[i] + Vadj[j]) - Sc[i * MAXCLS + j], 0.f);
            partial += h * h;
            count++;
        }
    }
    for (int off = 32; off > 0; off >>= 1) {
        partial += __shfl_down(partial, off);
        count   += __shfl_down(count, off);
    }
    const int lane = tid & 63, wv = tid >> 6;
    if (lane == 0) { ps[wv] = partial; cs[wv] = count; }
    __syncthreads();

    if (tid == 0) {
        float tot = ps[0] + ps[1] + ps[2] + ps[3];
        int   ct  = cs[0] + cs[1] + cs[2] + cs[3];
        atomicExch(&classLoss[c], tot);   // device-scope visible slot writes
        atomicExch(&classCnt[c], ct);
    }
    __syncthreads();

    // ---- last block reduces the 1024 class slots ----
    if (tid == 0) ps[0] = (float)atomicAdd(done, 1u);
    __syncthreads();
    if ((unsigned)ps[0] == 1023u) {
        double dls = 0.0;
        long long dct = 0;
        for (int k = tid; k < 1024; k += 256) {
            dls += (double)atomicAdd(&classLoss[k], 0.0f);   // coherent reads (distinct addrs)
            dct += (long long)atomicAdd(&classCnt[k], 0);
        }
        for (int off = 32; off > 0; off >>= 1) {
            dls += __shfl_down(dls, off);
            dct += __shfl_down(dct, off);
        }
        if (lane == 0) { dred[wv] = dls; cred[wv] = dct; }
        __syncthreads();
        if (tid == 0) {
            double ls = dred[0] + dred[1] + dred[2] + dred[3];
            long long np = cred[0] + cred[1] + cred[2] + cred[3];
            out[0] = (float)(ls / (2.0 * (double)np));
        }
    }
}

// ---------------- launch ----------------
extern "C" void kernel_launch(void* const* d_in, const int* in_sizes, int n_in,
                              void* d_out, int out_size, void* d_ws, size_t ws_size,
                              hipStream_t stream)
{
    const float* a      = (const float*)d_in[0];
    const float* b      = (const float*)d_in[1];
    const int*   labels = (const int*)d_in[2];
    float* out = (float*)d_out;

    char* ws = (char*)d_ws;
    // ws layout:
    //   [0, 2MB)   a_bf16 (scaled by log2e)    [2MB, 4MB)  b_bf16
    //   base2 = 4MB:
    //     +0       cnt[1024]            4096 B   (memset 0)
    //     +4096    done (uint)             4 B   (memset 0)
    //     +8192    classLoss[1024] f32  4096 B   (written unconditionally)
    //     +12288   classCnt[1024] int   4096 B
    //     +16384   list[1024*64]        256 KB
    //     +278528  Vp[8*8192] f32       256 KB
    unsigned short* abf = (unsigned short*)ws;
    unsigned short* bbf = (unsigned short*)(ws + 2097152);
    char*     base2     = ws + 4194304;
    int*      cnt       = (int*)(base2);
    unsigned* done      = (unsigned*)(base2 + 4096);
    float*    classLoss = (float*)(base2 + 8192);
    int*      classCnt  = (int*)(base2 + 12288);
    int*      list      = (int*)(base2 + 16384);
    float*    Vp        = (float*)(base2 + 278528);

    (void)hipMemsetAsync(base2, 0, 4100, stream);

    ml_convert_kernel<<<2048, 256, 0, stream>>>(a, b, labels, abf, bbf, cnt, list);

    dim3 g(NCHUNK, NN / 64);
    ml_vsum_gemm_kernel<<<g, 256, 0, stream>>>(abf, bbf, Vp);

    ml_pairs_kernel<<<1024, 256, 0, stream>>>(a, b, cnt, list, Vp, classLoss, classCnt, done, out);
}

// Round 11
// 104.372 us; speedup vs baseline: 2.5220x; 1.1323x over previous
//
#include <hip/hip_runtime.h>

#define NN 8192
#define DD 128
#define MAXCLS 64   // max members per class; Binom(8192,1/1024) mean 8 -> P(>64) negligible
#define NCHUNK 8    // j-chunks; GEMM grid = NCHUNK x 64 = 512 blocks = 2/CU
#define LOG2E 1.4426950408889634f
#define E1    2.718281828459045f   // e^margin, margin = 1

typedef __attribute__((ext_vector_type(8))) short bf16x8;
typedef __attribute__((ext_vector_type(4))) float f32x4;

#if __has_builtin(__builtin_amdgcn_exp2f)
#define EXP2F(x) __builtin_amdgcn_exp2f(x)
#else
#define EXP2F(x) exp2f(x)
#endif

// async global->LDS 16B: per-lane global address, LDS dest = wave-uniform base + lane*16
__device__ __forceinline__ void load16_lds(const unsigned short* g, unsigned short* l) {
    __builtin_amdgcn_global_load_lds(
        (const __attribute__((address_space(1))) unsigned int*)g,
        (__attribute__((address_space(3))) unsigned int*)l,
        16, 0, 0);
}

// ---------------- K0: fp32 -> bf16 (RNE) convert + class bucketing ----------------
__device__ __forceinline__ unsigned short f2bf(float x) {
    unsigned u = __float_as_uint(x);
    u = (u + 0x7FFFu + ((u >> 16) & 1u)) >> 16;
    return (unsigned short)u;
}

__global__ __launch_bounds__(256) void ml_convert_kernel(
    const float* __restrict__ a, const float* __restrict__ b,
    const int* __restrict__ labels,
    unsigned short* __restrict__ abf, unsigned short* __restrict__ bbf,
    int* __restrict__ cnt, int* __restrict__ list)
{
    int t = blockIdx.x * 256 + threadIdx.x;       // 0 .. 524287
    const float* src = a;
    unsigned short* dst = abf;
    int idx = t;
    float scale = LOG2E;                           // A rows carry the log2e factor
    if (t >= 262144) { src = b; dst = bbf; idx = t - 262144; scale = 1.0f; }
    float4 v = ((const float4*)src)[idx];
    ushort4 o;
    o.x = f2bf(v.x * scale); o.y = f2bf(v.y * scale);
    o.z = f2bf(v.z * scale); o.w = f2bf(v.w * scale);
    ((ushort4*)dst)[idx] = o;

    if (t < NN) {   // fused bucket append (cnt pre-zeroed by memset; ~8 adds/address)
        int c = labels[t];
        int p = atomicAdd(&cnt[c], 1);
        if (p < MAXCLS) list[c * MAXCLS + p] = t;
    }
}

// ---------------- K1: flash-style GEMM + unmasked exp2 row-sum -> Vp partials ----------------
// EXACT R6 structure (best measured): 128-row blocks, grid (NCHUNK, 64) = 512 = 2/CU.
// A staged once (fragments register-resident); 16 B-tiles of 64 cols, double-buffered.
// LDS swizzle: row r, 16B-chunk c at pos (c ^ (r&7)) -> DMA-linear AND conflict-free b128.
// R10's 64-row tile regressed (+4.6us): halving rows doubles total B-staging traffic.
__global__ __launch_bounds__(256, 2) void ml_vsum_gemm_kernel(
    const unsigned short* __restrict__ abf, const unsigned short* __restrict__ bbf,
    float* __restrict__ Vp)
{
    __shared__ unsigned short As[128 * DD];       // 32 KB
    __shared__ unsigned short Bs[2][64 * DD];     // 2 x 16 KB
    __shared__ float red[2][64];                  // cross-wave V combine

    const int tid  = threadIdx.x;
    const int lane = tid & 63;
    const int wv   = tid >> 6;
    const int row0 = blockIdx.y * 128;
    const int j0   = blockIdx.x * 1024;

    const int lr = lane >> 4;      // staging: row-within-4
    const int sp = lane & 15;      // staging: slot
    const int m  = lane & 15;      // mfma row/col lane
    const int q  = lane >> 4;
    const int xr = m & 7;          // read-side swizzle key

    // ---- issue A (once) + B tiles 0,1 ----
#pragma unroll
    for (int i = 0; i < 8; i++) {
        int rb = wv * 32 + i * 4;
        int r  = rb + lr;
        int cc = sp ^ (r & 7);
        load16_lds(&abf[(size_t)(row0 + r) * DD + cc * 8], &As[rb * DD]);
    }
#pragma unroll
    for (int i = 0; i < 4; i++) {
        int rb = wv * 16 + i * 4;
        int r  = rb + lr;
        int cc = sp ^ (r & 7);
        load16_lds(&bbf[(size_t)(j0 + r) * DD + cc * 8], &Bs[0][rb * DD]);
    }
#pragma unroll
    for (int i = 0; i < 4; i++) {
        int rb = wv * 16 + i * 4;
        int r  = rb + lr;
        int cc = sp ^ (r & 7);
        load16_lds(&bbf[(size_t)(j0 + 64 + r) * DD + cc * 8], &Bs[1][rb * DD]);
    }
    __syncthreads();

    const int wi = (wv >> 1) * 64;   // row-half
    const int wj = (wv & 1) * 32;    // col-half of the 64-col tile

    // ---- A fragments -> registers (read once) ----
    bf16x8 afr[4][4];
#pragma unroll
    for (int ti = 0; ti < 4; ti++)
#pragma unroll
        for (int ks = 0; ks < 4; ks++) {
            int r   = wi + ti * 16 + m;
            int pos = (ks * 4 + q) ^ xr;
            afr[ti][ks] = *(const bf16x8*)(&As[r * DD + pos * 8]);
        }

    float rs[4][4];
#pragma unroll
    for (int ti = 0; ti < 4; ti++)
#pragma unroll
        for (int rg = 0; rg < 4; rg++) rs[ti][rg] = 0.f;

    const f32x4 zero = {0.f, 0.f, 0.f, 0.f};

    // ---- j-tile loop: 16 tiles of 64 cols, double-buffered ----
#pragma unroll 2
    for (int jt = 0; jt < 16; jt++) {
        const int pb = jt & 1;
        f32x4 acc[4][2];
#pragma unroll
        for (int ti = 0; ti < 4; ti++)
#pragma unroll
            for (int tj = 0; tj < 2; tj++) acc[ti][tj] = zero;

#pragma unroll
        for (int ks = 0; ks < 4; ks++) {
            bf16x8 bfr[2];
#pragma unroll
            for (int tj = 0; tj < 2; tj++) {
                int r   = wj + tj * 16 + m;
                int pos = (ks * 4 + q) ^ xr;
                bfr[tj] = *(const bf16x8*)(&Bs[pb][r * DD + pos * 8]);
            }
#pragma unroll
            for (int ti = 0; ti < 4; ti++)
#pragma unroll
                for (int tj = 0; tj < 2; tj++)
                    acc[ti][tj] = __builtin_amdgcn_mfma_f32_16x16x32_bf16(afr[ti][ks], bfr[tj], acc[ti][tj], 0, 0, 0);
        }

        // epilogue: unmasked exp2 accumulate (A pre-scaled by log2e -> exp2(acc)=exp(S))
#pragma unroll
        for (int ti = 0; ti < 4; ti++)
#pragma unroll
            for (int tj = 0; tj < 2; tj++) {
                f32x4 c = acc[ti][tj];
                rs[ti][0] += EXP2F(c[0]);
                rs[ti][1] += EXP2F(c[1]);
                rs[ti][2] += EXP2F(c[2]);
                rs[ti][3] += EXP2F(c[3]);
            }

        __syncthreads();   // drains prefetch issued ~1 tile ago + all reads of buf[pb] done
        if (jt < 14) {
            int jb = j0 + (jt + 2) * 64;
#pragma unroll
            for (int i = 0; i < 4; i++) {
                int rb = wv * 16 + i * 4;
                int r  = rb + lr;
                int cc = sp ^ (r & 7);
                load16_lds(&bbf[(size_t)(jb + r) * DD + cc * 8], &Bs[pb][rb * DD]);
            }
        }
    }

    // ---- reduce over the 16 col-lanes ----
#pragma unroll
    for (int ti = 0; ti < 4; ti++)
#pragma unroll
        for (int rg = 0; rg < 4; rg++) {
            float v = rs[ti][rg];
            v += __shfl_xor(v, 1);
            v += __shfl_xor(v, 2);
            v += __shfl_xor(v, 4);
            v += __shfl_xor(v, 8);
            rs[ti][rg] = v;
        }

    // ---- cross-wave combine (col-half waves deposit; col-base waves add + store) ----
    if ((wv & 1) == 1 && m == 0) {
#pragma unroll
        for (int ti = 0; ti < 4; ti++)
#pragma unroll
            for (int rg = 0; rg < 4; rg++)
                red[wv >> 1][ti * 16 + q * 4 + rg] = rs[ti][rg];
    }
    __syncthreads();
    if ((wv & 1) == 0 && m == 0) {
#pragma unroll
        for (int ti = 0; ti < 4; ti++)
#pragma unroll
            for (int rg = 0; rg < 4; rg++) {
                int rloc = ti * 16 + q * 4 + rg;
                Vp[(size_t)blockIdx.x * NN + row0 + wi + rloc] = rs[ti][rg] + red[wv >> 1][rloc];
            }
    }
}

// ---------------- K2: per-class exact fp32 dots, V-adjust, hinge^2 -> slot stores ----------------
// R11: NO done-counter / last-block reduce (1024 same-address device RMWs ~ 10-15us of
// serialized atomic-queue time -- same pathology as R4's 46us pairs kernel). Plain
// stores to per-class slots; kernel-boundary release makes them visible to K3.
__global__ __launch_bounds__(256) void ml_pairs_kernel(
    const float* __restrict__ a, const float* __restrict__ b,
    const int* __restrict__ cnt, const int* __restrict__ list,
    const float* __restrict__ Vp,
    float* __restrict__ classLoss, int* __restrict__ classCnt)
{
    __shared__ int   mem[MAXCLS];
    __shared__ float sumExp[MAXCLS];
    __shared__ float Vadj[MAXCLS];
    __shared__ float Sc[MAXCLS * MAXCLS];   // 16 KB
    __shared__ float ps[4];
    __shared__ int   cs[4];

    const int c   = blockIdx.x;
    const int tid = threadIdx.x;
    int mc = cnt[c];
    if (mc > MAXCLS) mc = MAXCLS;

    float vsum = 0.f;
    if (tid < mc) {
        int r = list[c * MAXCLS + tid];
        mem[tid] = r;
#pragma unroll
        for (int jc = 0; jc < NCHUNK; jc++) vsum += Vp[(size_t)jc * NN + r];
    }
    if (tid < MAXCLS) sumExp[tid] = 0.f;
    __syncthreads();

    // ---- phase 1: mc^2 dots (16-lane groups), cache S, accumulate exp sums ----
    const int g = tid >> 4;                   // 16 groups
    const int l = tid & 15;
    const int tot1 = mc * mc;
    for (int pp = g; pp < tot1; pp += 16) {
        int i = pp / mc;
        int j = pp - i * mc;
        int ri = mem[i], rj = mem[j];
        const float4* ar = (const float4*)(a + (size_t)ri * DD) + l * 2;
        const float4* br = (const float4*)(b + (size_t)rj * DD) + l * 2;
        float4 a0 = ar[0], a1 = ar[1];
        float4 b0 = br[0], b1 = br[1];
        float s = 0.f;
        s = fmaf(a0.x, b0.x, s); s = fmaf(a0.y, b0.y, s);
        s = fmaf(a0.z, b0.z, s); s = fmaf(a0.w, b0.w, s);
        s = fmaf(a1.x, b1.x, s); s = fmaf(a1.y, b1.y, s);
        s = fmaf(a1.z, b1.z, s); s = fmaf(a1.w, b1.w, s);
        s += __shfl_xor(s, 1);
        s += __shfl_xor(s, 2);
        s += __shfl_xor(s, 4);
        s += __shfl_xor(s, 8);
        if (l == 0) {
            Sc[i * MAXCLS + j] = s;
            atomicAdd(&sumExp[i], __expf(s));   // LDS atomic, per-block
        }
    }
    __syncthreads();

    if (tid < mc) Vadj[tid] = E1 * (vsum - sumExp[tid]);
    __syncthreads();

    // ---- phase 2: one thread per ordered pair (i != j) ----
    float partial = 0.f;
    int   count   = 0;
    for (int pp = tid; pp < tot1; pp += 256) {
        int i = pp / mc;
        int j = pp - i * mc;
        if (i != j) {
            float h = fmaxf(logf(Vadj[i] + Vadj[j]) - Sc[i * MAXCLS + j], 0.f);
            partial += h * h;
            count++;
        }
    }
    for (int off = 32; off > 0; off >>= 1) {
        partial += __shfl_down(partial, off);
        count   += __shfl_down(count, off);
    }
    const int lane = tid & 63, wv = tid >> 6;
    if (lane == 0) { ps[wv] = partial; cs[wv] = count; }
    __syncthreads();
    if (tid == 0) {
        classLoss[c] = ps[0] + ps[1] + ps[2] + ps[3];   // plain stores (distinct addrs)
        classCnt[c]  = cs[0] + cs[1] + cs[2] + cs[3];
    }
}

// ---------------- K3: finalize (1 block) ----------------
__global__ __launch_bounds__(256) void ml_finalize_kernel(
    const float* __restrict__ classLoss, const int* __restrict__ classCnt,
    float* __restrict__ out)
{
    __shared__ double dred[4];
    __shared__ long long cred[4];
    const int tid = threadIdx.x;
    const int lane = tid & 63, wv = tid >> 6;

    double dls = 0.0;
    long long dct = 0;
    for (int k = tid; k < 1024; k += 256) {
        dls += (double)classLoss[k];
        dct += (long long)classCnt[k];
    }
    for (int off = 32; off > 0; off >>= 1) {
        dls += __shfl_down(dls, off);
        dct += __shfl_down(dct, off);
    }
    if (lane == 0) { dred[wv] = dls; cred[wv] = dct; }
    __syncthreads();
    if (tid == 0) {
        double ls = dred[0] + dred[1] + dred[2] + dred[3];
        long long np = cred[0] + cred[1] + cred[2] + cred[3];
        out[0] = (float)(ls / (2.0 * (double)np));
    }
}

// ---------------- launch ----------------
extern "C" void kernel_launch(void* const* d_in, const int* in_sizes, int n_in,
                              void* d_out, int out_size, void* d_ws, size_t ws_size,
                              hipStream_t stream)
{
    const float* a      = (const float*)d_in[0];
    const float* b      = (const float*)d_in[1];
    const int*   labels = (const int*)d_in[2];
    float* out = (float*)d_out;

    char* ws = (char*)d_ws;
    // ws layout:
    //   [0, 2MB)   a_bf16 (scaled by log2e)    [2MB, 4MB)  b_bf16
    //   base2 = 4MB:
    //     +0       cnt[1024]            4096 B   (memset 0)
    //     +8192    classLoss[1024] f32  4096 B   (written unconditionally by K2)
    //     +12288   classCnt[1024] int   4096 B
    //     +16384   list[1024*64]        256 KB
    //     +278528  Vp[8*8192] f32       256 KB
    unsigned short* abf = (unsigned short*)ws;
    unsigned short* bbf = (unsigned short*)(ws + 2097152);
    char*     base2     = ws + 4194304;
    int*      cnt       = (int*)(base2);
    float*    classLoss = (float*)(base2 + 8192);
    int*      classCnt  = (int*)(base2 + 12288);
    int*      list      = (int*)(base2 + 16384);
    float*    Vp        = (float*)(base2 + 278528);

    (void)hipMemsetAsync(cnt, 0, 4096, stream);

    ml_convert_kernel<<<2048, 256, 0, stream>>>(a, b, labels, abf, bbf, cnt, list);

    dim3 g(NCHUNK, NN / 128);
    ml_vsum_gemm_kernel<<<g, 256, 0, stream>>>(abf, bbf, Vp);

    ml_pairs_kernel<<<1024, 256, 0, stream>>>(a, b, cnt, list, Vp, classLoss, classCnt);

    ml_finalize_kernel<<<1, 256, 0, stream>>>(classLoss, classCnt, out);
}